// Round 3
// baseline (90.686 us; speedup 1.0000x reference)
//
#include <hip/hip_runtime.h>
#include <math.h>

#define BB 2048
#define CC 1000
#define DD 64
constexpr float EPS_STATS = 1e-5f;
constexpr float EPS_PREC  = 1e-6f;
constexpr float TSUM = (float)BB + (float)CC * EPS_STATS;  // counts.sum()

// --- K1: per-class stats, no atomics, no pre-zero. 250 blocks x 256 thr.
// Block owns 4 classes. Scan y (LDS) with wave-uniform compares; gather z rows.
// Emits meanT (DxC), ncntf (C), pooledPart (250 x D) — all written exactly once.
__global__ void __launch_bounds__(256)
k_stats1(const float* __restrict__ z, const int* __restrict__ y,
         float* __restrict__ meanT, float* __restrict__ ncntf,
         float* __restrict__ pooledPart) {
    __shared__ __align__(16) int ys[BB];
    __shared__ float part[4][DD];
    int tid = threadIdx.x;
    #pragma unroll
    for (int i = 0; i < BB / 256; ++i) ys[tid + i * 256] = y[tid + i * 256];
    __syncthreads();

    int d  = tid & 63;
    int cl = tid >> 6;                  // 0..3
    int c  = blockIdx.x * 4 + cl;       // class id (all 64 lanes of a wave share c)

    float s = 0.f, q = 0.f;
    int n = 0;
    for (int b = 0; b < BB; b += 4) {
        int4 yy = *reinterpret_cast<const int4*>(&ys[b]);  // LDS broadcast
        // conditions are wave-uniform -> s_cbranch skips the loads entirely
        if (yy.x == c) { float v = z[(b + 0) * DD + d]; s += v; q = fmaf(v, v, q); ++n; }
        if (yy.y == c) { float v = z[(b + 1) * DD + d]; s += v; q = fmaf(v, v, q); ++n; }
        if (yy.z == c) { float v = z[(b + 2) * DD + d]; s += v; q = fmaf(v, v, q); ++n; }
        if (yy.w == c) { float v = z[(b + 3) * DD + d]; s += v; q = fmaf(v, v, q); ++n; }
    }
    float nn = (float)n;
    float ce = nn + EPS_STATS;
    float m  = s / ce;
    meanT[d * CC + c] = m;              // scattered, tiny, L2-resident
    if (d == 0) ncntf[c] = nn;

    // pooled-cov contribution of this class at dim d:  q - 2ms + n m^2
    part[cl][d] = fmaf(nn * m, m, fmaf(-2.f * m, s, q));
    __syncthreads();
    if (tid < DD) {
        pooledPart[blockIdx.x * DD + tid] =
            part[0][tid] + part[1][tid] + part[2][tid] + part[3][tid];
    }
}

// --- K2: scoring. Grid (B/ROWS, C/256). 256 thr = 256 classes, ROWS b-rows.
// Phase A: reduce pooledPart -> precision (redundant per block, L2-cheap).
// Phase B: m2 = S_r - 2*sum_d w_d z_rd + K_c with w = p*m (1 FMA per (r,d)).
#define ROWS 16
#define CTILE 256
__global__ void __launch_bounds__(256)
k_score(const float* __restrict__ z, const float* __restrict__ meanT,
        const float* __restrict__ ncntf, const float* __restrict__ pooledPart,
        float* __restrict__ out) {
    __shared__ float zs[ROWS][DD];   // 4 KB
    __shared__ float ps[DD];
    __shared__ float red[4][DD];
    __shared__ float sr[ROWS];
    int tid = threadIdx.x;
    int d = tid & 63;
    int chunk = tid >> 6;

    // Phase A: precision from pooled partials (250 rows of 64)
    float acc = 0.f;
    for (int p = chunk; p < 250; p += 4) acc += pooledPart[p * DD + d];  // coalesced
    red[chunk][d] = acc;

    // load z tile (16 rows) concurrently
    int b0 = blockIdx.x * ROWS;
    #pragma unroll
    for (int i = 0; i < (ROWS * DD) / 256; ++i) {
        int idx = tid + i * 256;
        zs[idx >> 6][idx & 63] = z[b0 * DD + idx];
    }
    __syncthreads();
    if (tid < DD) {
        float pooled = (red[0][tid] + red[1][tid] + red[2][tid] + red[3][tid]) / TSUM
                       + EPS_STATS;
        ps[tid] = 1.0f / fmaxf(pooled, EPS_PREC);
    }
    __syncthreads();

    // S_r = sum_d p_d * z_rd^2  (per-row, shared across all classes)
    if (tid < ROWS) {
        float a = 0.f;
        #pragma unroll 16
        for (int dd = 0; dd < DD; ++dd) {
            float v = zs[tid][dd];
            a = fmaf(ps[dd] * v, v, a);
        }
        sr[tid] = a;
    }
    __syncthreads();

    int c  = blockIdx.y * CTILE + tid;
    int cc = (c < CC) ? c : (CC - 1);
    float logp = logf((ncntf[cc] + EPS_STATS) / TSUM);

    float dot[ROWS];
    #pragma unroll
    for (int r = 0; r < ROWS; ++r) dot[r] = 0.f;
    float K = 0.f;

    #pragma unroll 8
    for (int dd = 0; dd < DD; ++dd) {
        float m = meanT[dd * CC + cc];   // coalesced across lanes
        float w = ps[dd] * m;            // LDS broadcast + mul
        K = fmaf(w, m, K);               // sum_d p m^2
        #pragma unroll
        for (int r = 0; r < ROWS; ++r)
            dot[r] = fmaf(w, zs[r][dd], dot[r]);   // 1 LDS + 1 FMA
    }

    if (c < CC) {
        #pragma unroll
        for (int r = 0; r < ROWS; ++r) {
            float m2 = sr[r] - 2.f * dot[r] + K;
            out[(size_t)(b0 + r) * CC + c] = fmaf(-0.5f, m2, logp);
        }
    }
}

extern "C" void kernel_launch(void* const* d_in, const int* in_sizes, int n_in,
                              void* d_out, int out_size, void* d_ws, size_t ws_size,
                              hipStream_t stream) {
    const float* z = (const float*)d_in[0];
    const int*   y = (const int*)d_in[1];
    float* out = (float*)d_out;

    // ws layout — everything is written-once by K1 before K2 reads it: no zeroing.
    float* meanT      = (float*)d_ws;        // D*C = 64000
    float* ncntf      = meanT + DD * CC;     // 1000
    float* pooledPart = ncntf + CC;          // 250*64 = 16000

    k_stats1<<<250, 256, 0, stream>>>(z, y, meanT, ncntf, pooledPart);
    dim3 grid(BB / ROWS, (CC + CTILE - 1) / CTILE);
    k_score<<<grid, 256, 0, stream>>>(z, meanT, ncntf, pooledPart, out);
}